// Round 10
// baseline (243.121 us; speedup 1.0000x reference)
//
#include <hip/hip_runtime.h>
#include <math.h>

typedef __attribute__((ext_vector_type(8))) short s16x8;
typedef __attribute__((ext_vector_type(4))) float f32x4;

__device__ __forceinline__ float b2f(unsigned short u) {
    unsigned int x = ((unsigned int)u) << 16;
    float f; __builtin_memcpy(&f, &x, 4); return f;
}
__device__ __forceinline__ unsigned short f2b(float f) {
    unsigned int x; __builtin_memcpy(&x, &f, 4);
    unsigned int r = x + 0x7FFFu + ((x >> 16) & 1u);
    return (unsigned short)(r >> 16);
}

// async global->LDS, 16B per lane, linear LDS dest (guide §5 / m97)
#define GLDS(g, l) __builtin_amdgcn_global_load_lds( \
    (const __attribute__((address_space(1))) unsigned int*)(g), \
    (__attribute__((address_space(3))) unsigned int*)(l), 16, 0, 0)

// ---------- fused prep: x-transpose, W-transpose, weight-norm, zero-init ----------
// flat grid: [0,4096) txp_x | [4096,4288) txp_w | [4288,4800) wnorm | [4800,4864) init
__global__ __launch_bounds__(256) void prep_k(const float* __restrict__ x, unsigned short* __restrict__ xT,
                                              const float* __restrict__ Wq, const float* __restrict__ Wk,
                                              const float* __restrict__ Wv, unsigned short* __restrict__ WT,
                                              const float* __restrict__ v1, const float* __restrict__ g1,
                                              unsigned short* __restrict__ w1K,
                                              const float* __restrict__ v2, const float* __restrict__ g2,
                                              unsigned short* __restrict__ w2K,
                                              unsigned short* __restrict__ attT, unsigned short* __restrict__ h1T,
                                              float* __restrict__ colD) {
    __shared__ float t[32][33];
    __shared__ float red[256];
    int bid = blockIdx.x, tid = threadIdx.x;
    if (bid < 4096) {               // x [b][c][t] -> xT [b][t][c] bf16
        int tt = bid & 31, ct = (bid >> 5) & 7, b = bid >> 8;
        int col = tid & 31, rq = tid >> 5;
        const float* xb = x + (((size_t)b * 256 + ct * 32) << 10) + (tt << 5);
#pragma unroll
        for (int p = 0; p < 4; ++p) { int r = rq + p * 8; t[r][col] = xb[((size_t)r << 10) + col]; }
        __syncthreads();
        unsigned short* o = xT + ((size_t)b << 18) + ((size_t)(tt << 5) << 8) + (ct << 5);
#pragma unroll
        for (int p = 0; p < 4; ++p) { int tr = rq + p * 8; o[((size_t)tr << 8) + col] = f2b(t[col][tr]); }
    } else if (bid < 4288) {        // W [c][k] -> WT [k][c] bf16 (3 mats)
        int id = bid - 4096;
        int kt = id & 7, ct = (id >> 3) & 7, z = id >> 6;
        const float* W = (z == 0) ? Wq : (z == 1) ? Wk : Wv;
        int col = tid & 31, rq = tid >> 5;
        const float* wb = W + ((ct * 32) << 8) + (kt << 5);
#pragma unroll
        for (int p = 0; p < 4; ++p) { int r = rq + p * 8; t[r][col] = wb[(r << 8) + col]; }
        __syncthreads();
        unsigned short* o = WT + (z << 16) + ((kt << 5) << 8) + (ct << 5);
#pragma unroll
        for (int p = 0; p < 4; ++p) { int tr = rq + p * 8; o[(tr << 8) + col] = f2b(t[col][tr]); }
    } else if (bid < 4800) {        // weight-norm -> wK [kk][o][ci] bf16
        int id = bid - 4288;
        int o = id & 255;
        const float* v = (id >= 256) ? v2 : v1;
        const float* g = (id >= 256) ? g2 : g1;
        unsigned short* wK = (id >= 256) ? w2K : w1K;
        float a0 = v[o * 768 + tid * 3 + 0];
        float a1 = v[o * 768 + tid * 3 + 1];
        float a2 = v[o * 768 + tid * 3 + 2];
        red[tid] = a0 * a0 + a1 * a1 + a2 * a2; __syncthreads();
        for (int off = 128; off > 0; off >>= 1) {
            if (tid < off) red[tid] += red[tid + off];
            __syncthreads();
        }
        float sc = g[o] / sqrtf(red[0]);
        wK[0 * 65536 + o * 256 + tid] = f2b(a0 * sc);
        wK[1 * 65536 + o * 256 + tid] = f2b(a1 * sc);
        wK[2 * 65536 + o * 256 + tid] = f2b(a2 * sc);
    } else {                        // zero pads + colD
        int idx = (bid - 4800) * 256 + tid;  // 0..16383
        colD[idx] = 0.f;
        if (idx < 8192) {
            int b = idx >> 9, r = idx & 511;
            attT[(size_t)b * 262656 + r] = 0;
            h1T[(size_t)b * 262656 + r] = 0;
        }
    }
}

// ---------- generic bf16 MFMA GEMM: C = A . B^T  (A [M][K], B [N][K], K-contiguous) ----------
// 128x64 tile, 256 thr = 4 waves (2M x 2N), each wave 64x32 = 4x2 frags of 16x16x32.
// 3-buffer GLDS rotation + COUNTED vmcnt(3) (T4: 3 GLDS/thread/stage) + one s_barrier/step.
//   Safety: stage(s) writes buf(s%3); next overwrite is stage(s+3) issued at iter s+1 AFTER
//   the iter-s+1 barrier; all iter-s readers of buf(s%3) issued their reads before it.
// LDS bank swizzle (T2, rule #21): physical 16B-slot p of row r holds global slot
//   p ^ ((r>>1)&3); staged via pre-swizzled GLOBAL source col + linear LDS dest; read with
//   the same XOR. All wave row-offsets are multiples of 8 -> per-lane constant.
// Occupancy: LDS 36-41 KB -> 3-4 blocks/CU; grids 512-1536 live blocks (2-6/CU) so staging
//   bursts from independent blocks overlap each other's latency stalls.
// MODE 0: merged q/k/v projections (grid 16,18,16; y<16: q/k N=256, y>=16: v N=1024)
// MODE 2: scores  E = exp(qk/16) bf16, masked->0, skip nt>2mt+1; fused colsum -> colD
// MODE 3: PV  A=E, B=vTs(=v/colD), K=(mt+1)*128; nt==0 fuses rowsum via Rs recip table
// MODE 4: conv1 (+ blockIdx.z==16, x<2: wx softmax over rowsums)
// MODE 5: conv2 + bias relu + x*(1+wx) residual, relu, out fp32 [o][t]
template<int MODE>
__global__ __launch_bounds__(256) void gemm_k(
        const unsigned short* __restrict__ Ab, const unsigned short* __restrict__ Bb,
        unsigned short* __restrict__ o16, unsigned short* __restrict__ o16b,
        unsigned short* __restrict__ o16c, float* __restrict__ o32,
        const float* __restrict__ bias, const float* __restrict__ bias2,
        const float* __restrict__ bias3, const float* __restrict__ xres,
        const float* __restrict__ wxv, float* __restrict__ wxout, int b0) {
    int tid = threadIdx.x;

    if constexpr (MODE == 4) {      // fused wx block (z==16): softmax_t over rowsums
        if (blockIdx.z == 16) {
            if (blockIdx.x >= 2) return;
            __shared__ float wxr[8];
            int b = ((int)blockIdx.y << 1) + (int)blockIdx.x;
            float4 r = ((const float4*)(xres + ((size_t)b << 10)))[tid];
            float mx = fmaxf(fmaxf(r.x, r.y), fmaxf(r.z, r.w));
#pragma unroll
            for (int off = 32; off > 0; off >>= 1) mx = fmaxf(mx, __shfl_xor(mx, off, 64));
            if ((tid & 63) == 0) wxr[tid >> 6] = mx;
            __syncthreads();
            float M = fmaxf(fmaxf(wxr[0], wxr[1]), fmaxf(wxr[2], wxr[3]));
            float e0 = expf(r.x - M), e1 = expf(r.y - M), e2 = expf(r.z - M), e3 = expf(r.w - M);
            float ss = e0 + e1 + e2 + e3;
#pragma unroll
            for (int off = 32; off > 0; off >>= 1) ss += __shfl_xor(ss, off, 64);
            if ((tid & 63) == 0) wxr[4 + (tid >> 6)] = ss;
            __syncthreads();
            float Z = wxr[4] + wxr[5] + wxr[6] + wxr[7];
            ((float4*)(wxout + ((size_t)b << 10)))[tid] =
                make_float4(e0 / Z, e1 / Z, e2 / Z, e3 / Z);
            return;
        }
    }

    int nt = blockIdx.x, yy = blockIdx.y, bz = blockIdx.z;
    if constexpr (MODE == 2) { if (nt > 2 * yy + 1) return; }
    bool isk = false, isv = false;
    int mt = yy;
    if constexpr (MODE == 0) {
        if (yy < 16) { if (nt >= 4) return; isk = (yy >= 8); mt = yy & 7; }
        else         { isv = true; mt = yy - 16; }
    }
    int b = b0 + bz;
    int m0 = mt << 7, n0 = nt << 6;
    constexpr int LDA = (MODE == 3) ? 1024 : 256;
    constexpr int LDB = (MODE == 3) ? 1024 : 256;
    const unsigned short* A;
    const unsigned short* B;
    if constexpr (MODE == 0) {
        A = isv ? (Bb + 131072) : (Ab + ((size_t)b << 18));          // v: A = WvT
        B = isv ? (Ab + ((size_t)b << 18)) : (isk ? Bb + 65536 : Bb);
    } else if constexpr (MODE == 2) { A = Ab + ((size_t)b << 18); B = Bb + ((size_t)b << 18); }
    else if constexpr (MODE == 3)   { A = Ab + ((size_t)bz << 20); B = Bb + ((size_t)b << 18); }
    else                            { A = Ab + (size_t)b * 262656; B = Bb; }

    int wid = tid >> 6, lane = tid & 63;
    int wr = wid >> 1, wc = wid & 1;            // 2 x 2 waves
    int lrow = lane & 15, koct = lane >> 4;
    int srow = tid >> 2;                        // staging row 0..63 (A: +0 / +64)
    int scg  = tid & 3;
    int sscol = ((scg ^ ((srow >> 1) & 3)) << 3);   // pre-swizzled global col (shorts)
    int rswz = (koct ^ ((lrow >> 1) & 3)) << 3;     // swizzled read slot (per-lane const)

    __shared__ short As[3][4096];               // 128 x 32
    __shared__ short Bs[3][2048];               // 64 x 32
    __shared__ float Rs[(MODE == 3) ? 1024 : 4];

    int ksteps = (MODE == 3) ? ((mt + 1) << 2) : 8;
    constexpr int NSEG = (MODE >= 4) ? 3 : 1;
    int total = NSEG * ksteps;

    if constexpr (MODE == 3) {
        if (nt == 0) {
            for (int i = tid; i < (ksteps << 5); i += 256)
                Rs[i] = 1.f / bias[(b << 10) + i];
        }
    }
    float racc = 0.f;

    f32x4 acc[4][2];
#pragma unroll
    for (int m = 0; m < 4; ++m)
#pragma unroll
        for (int n = 0; n < 2; ++n) acc[m][n] = (f32x4){0.f, 0.f, 0.f, 0.f};

    auto stage_to = [&](int s, int bufi) {
        const unsigned short *ga0, *ga1, *gb;
        if constexpr (MODE >= 4) {
            int seg = s >> 3, k0 = (s & 7) << 5;
            ga0 = A + (size_t)(m0 + seg + srow) * 256 + k0 + sscol;
            ga1 = A + (size_t)(m0 + seg + srow + 64) * 256 + k0 + sscol;
            gb  = B + (seg << 16) + (size_t)(n0 + srow) * 256 + k0 + sscol;
        } else {
            int k0 = s << 5;
            ga0 = A + (size_t)(m0 + srow) * LDA + k0 + sscol;
            ga1 = A + (size_t)(m0 + srow + 64) * LDA + k0 + sscol;
            gb  = B + (size_t)(n0 + srow) * LDB + k0 + sscol;
        }
        GLDS(ga0, &As[bufi][tid << 3]);
        GLDS(ga1, &As[bufi][2048 + (tid << 3)]);
        GLDS(gb,  &Bs[bufi][tid << 3]);
    };

    stage_to(0, 0);
    stage_to(1, 1);
    for (int s = 0; s < total; ++s) {
        if (s + 1 < total) asm volatile("s_waitcnt vmcnt(3)" ::: "memory");
        else               asm volatile("s_waitcnt vmcnt(0)" ::: "memory");
        __builtin_amdgcn_s_barrier();
        if (s + 2 < total) stage_to(s + 2, (s + 2) % 3);
        const short* as = &As[s % 3][0];
        const short* bs = &Bs[s % 3][0];
        s16x8 af[4], bf[2];
#pragma unroll
        for (int m = 0; m < 4; ++m)
            af[m] = *(const s16x8*)&as[(wr * 64 + m * 16 + lrow) * 32 + rswz];
#pragma unroll
        for (int n = 0; n < 2; ++n)
            bf[n] = *(const s16x8*)&bs[(wc * 32 + n * 16 + lrow) * 32 + rswz];
#pragma unroll
        for (int m = 0; m < 4; ++m)
#pragma unroll
            for (int n = 0; n < 2; ++n)
                acc[m][n] = __builtin_amdgcn_mfma_f32_16x16x32_bf16(af[m], bf[n], acc[m][n], 0, 0, 0);
        if constexpr (MODE == 3) {
            if (nt == 0) {   // fused rowsum from the LDS-resident E tile (swizzled read)
                int k0 = s << 5;
                int rrow = tid >> 1, half = tid & 1;
                int sx = (rrow >> 1) & 3;
#pragma unroll
                for (int h = 0; h < 2; ++h) {
                    int slot = (half << 1) + h;
                    const s16x8 e = *(const s16x8*)&as[rrow * 32 + ((slot ^ sx) << 3)];
#pragma unroll
                    for (int c = 0; c < 8; ++c)
                        racc += b2f((unsigned short)e[c]) * Rs[k0 + (slot << 3) + c];
                }
            }
        }
    }

    if constexpr (MODE == 3) {
        if (nt == 0) {
            float v = racc + __shfl_xor(racc, 1, 64);
            if ((tid & 1) == 0) o32[(b << 10) + m0 + (tid >> 1)] = v;
        }
    }

    int rb = m0 + wr * 64 + koct * 4;
    int cb = n0 + wc * 32 + lrow;

    if constexpr (MODE == 2) {
        float csum[2] = {0.f, 0.f};
#pragma unroll
        for (int m = 0; m < 4; ++m) {
#pragma unroll
            for (int n = 0; n < 2; ++n) {
                int col = cb + n * 16;
#pragma unroll
                for (int j = 0; j < 4; ++j) {
                    int row = rb + m * 16 + j;
                    float e = (col <= row) ? expf(acc[m][n][j] * 0.0625f) : 0.f;
                    o16[((size_t)bz << 20) + ((size_t)row << 10) + col] = f2b(e);
                    csum[n] += e;
                }
            }
        }
#pragma unroll
        for (int n = 0; n < 2; ++n) {
            float v = csum[n];
            v += __shfl_xor(v, 16, 64);
            v += __shfl_xor(v, 32, 64);
            if (koct == 0) atomicAdd(&o32[(b << 10) + cb + n * 16], v);
        }
        return;
    }

#pragma unroll
    for (int m = 0; m < 4; ++m) {
#pragma unroll
        for (int n = 0; n < 2; ++n) {
            int col = cb + n * 16;
#pragma unroll
            for (int j = 0; j < 4; ++j) {
                int row = rb + m * 16 + j;
                float v = acc[m][n][j];
                if constexpr (MODE == 0) {
                    if (isv)       o16c[((size_t)b << 18) + ((size_t)row << 10) + col] = f2b(v + bias3[row]);
                    else if (isk)  o16b[((size_t)b << 18) + ((size_t)row << 8) + col] = f2b(v + bias2[col]);
                    else           o16 [((size_t)b << 18) + ((size_t)row << 8) + col] = f2b(v + bias[col]);
                } else if constexpr (MODE == 3) {
                    o16[(size_t)b * 262656 + ((size_t)(row + 2) << 8) + col] = f2b(v);
                } else if constexpr (MODE == 4) {
                    o16[(size_t)b * 262656 + ((size_t)(row + 2) << 8) + col] =
                        f2b(fmaxf(v + bias[col], 0.f));
                } else if constexpr (MODE == 5) {
                    size_t oi = (((size_t)(b << 8) + col) << 10) + row;
                    float h = fmaxf(v + bias[col], 0.f);
                    h = fmaxf(h + xres[oi] * (1.f + wxv[(b << 10) + row]), 0.f);
                    o32[oi] = h;
                }
            }
        }
    }
}

// ---------- vTs = vT / colD (in place, per key index i) ----------
__global__ __launch_bounds__(256) void vscale_k(unsigned short* __restrict__ vT,
                                                const float* __restrict__ colD, int b0) {
    int c = blockIdx.x, bz = blockIdx.y, b = b0 + bz;
    int tid = threadIdx.x;
    unsigned short* row = vT + ((size_t)b << 18) + ((size_t)c << 10);
    ushort4 v4 = *(const ushort4*)&row[tid << 2];
    float4 d4 = ((const float4*)(colD + (b << 10)))[tid];
    ushort4 o;
    o.x = f2b(b2f(v4.x) / d4.x);
    o.y = f2b(b2f(v4.y) / d4.y);
    o.z = f2b(b2f(v4.z) / d4.z);
    o.w = f2b(b2f(v4.w) / d4.w);
    *(ushort4*)&row[tid << 2] = o;
}

extern "C" void kernel_launch(void* const* d_in, const int* in_sizes, int n_in,
                              void* d_out, int out_size, void* d_ws, size_t ws_size,
                              hipStream_t stream) {
    const float* x   = (const float*)d_in[0];
    const float* Wq  = (const float*)d_in[1];
    const float* bq  = (const float*)d_in[2];
    const float* Wk  = (const float*)d_in[3];
    const float* bk  = (const float*)d_in[4];
    const float* Wv  = (const float*)d_in[5];
    const float* bv  = (const float*)d_in[6];
    const float* c1v = (const float*)d_in[7];
    const float* c1g = (const float*)d_in[8];
    const float* c1b = (const float*)d_in[9];
    const float* c2v = (const float*)d_in[10];
    const float* c2g = (const float*)d_in[11];
    const float* c2b = (const float*)d_in[12];
    float* out = (float*)d_out;

    // ws layout in BYTES (all regions disjoint)
    char* w = (char*)d_ws;
    unsigned short* xT   = (unsigned short*)(w + 0);          // 8,388,608
    unsigned short* qb   = (unsigned short*)(w + 8388608);    // 8,388,608
    unsigned short* kb   = (unsigned short*)(w + 16777216);   // 8,388,608
    unsigned short* vT   = (unsigned short*)(w + 25165824);   // 8,388,608
    unsigned short* WT   = (unsigned short*)(w + 33554432);   //   393,216
    unsigned short* w1K  = (unsigned short*)(w + 33947648);   //   393,216
    unsigned short* w2K  = (unsigned short*)(w + 34340864);   //   393,216
    unsigned short* attT = (unsigned short*)(w + 34734080);   // 8,404,992 (1026 rows/b)
    unsigned short* h1T  = (unsigned short*)(w + 43139072);   // 8,404,992
    float* colD = (float*)(w + 51544064);                     //    65,536
    float* rows = (float*)(w + 51675136);                     //    65,536
    float* wxp  = (float*)(w + 51740672);                     //    65,536
    unsigned short* S = (unsigned short*)(w + 51806208);      // nb * 2,097,152

    dim3 blk(256);

    prep_k<<<dim3(4864), blk, 0, stream>>>(x, xT, Wq, Wk, Wv, WT,
                                           c1v, c1g, w1K, c2v, c2g, w2K,
                                           attT, h1T, colD);

    // merged q/k/v projections (y<16: q/k N=256 -> nt<4; y>=16: v N=1024 -> nt<16)
    gemm_k<0><<<dim3(16, 18, 16), blk, 0, stream>>>(xT, WT, qb, kb, vT, nullptr,
                                                    bq, bk, bv, nullptr, nullptr, nullptr, 0);

    // chunk the 2 MB/batch E buffer by available ws (deterministic in ws_size)
    size_t fixed = 51806208;
    size_t avail = (ws_size > fixed) ? ws_size - fixed : 0;
    int bmax = (int)(avail / 2097152);
    if (bmax < 1) bmax = 1;
    if (bmax > 16) bmax = 16;
    for (int b0 = 0; b0 < 16; b0 += bmax) {
        int nb = (16 - b0 < bmax) ? (16 - b0) : bmax;
        gemm_k<2><<<dim3(16, 8, nb), blk, 0, stream>>>(qb, kb, S, nullptr, nullptr, colD,
                                                       nullptr, nullptr, nullptr, nullptr,
                                                       nullptr, nullptr, b0);
        vscale_k<<<dim3(256, nb), blk, 0, stream>>>(vT, colD, b0);
        gemm_k<3><<<dim3(4, 8, nb), blk, 0, stream>>>(S, vT, attT, nullptr, nullptr, rows,
                                                      colD, nullptr, nullptr, nullptr,
                                                      nullptr, nullptr, b0);
    }
    // conv1 (+ wx in z==16 slice)
    gemm_k<4><<<dim3(4, 8, 17), blk, 0, stream>>>(attT, w1K, h1T, nullptr, nullptr, nullptr,
                                                  c1b, nullptr, nullptr, rows, nullptr, wxp, 0);
    gemm_k<5><<<dim3(4, 8, 16), blk, 0, stream>>>(h1T, w2K, nullptr, nullptr, nullptr, out,
                                                  c2b, nullptr, nullptr, x, wxp, nullptr, 0);
}